// Round 8
// baseline (69.091 us; speedup 1.0000x reference)
//
#include <hip/hip_runtime.h>
#include <math.h>

// TropConv2D: out[b,ho,wo,f] = max_k(patch + w) - min_k(patch + w) + bias
// B=8, H=W=32, C=32, KH=KW=3, F=64, Ho=Wo=30, K=288. 7200 output pixels.
//
// R10 = clean factorial cell: R4's winning x-path + occupancy (s_load x,
// 16 waves/CU, one barrier) combined with R5's transposed w-read
// (ds_read_b128) -- but with CONFLICT-FREE staging this time.
//
// Why: R4 (27.5us kernel, reproduced by R9 A/A) is DS-pipe-bound:
// 288 ds_read_b32 x 5.8cyc x 8 waves = 13.4k cyc/block serial on the
// LDS pipe vs 4.6k cyc VALU/SIMD. Transposed wT[f][k] rows make each
// lane's 4 k-values contiguous: 72 ds_read_b128 (12 cyc) instead ->
// DS term halves to 6.9k cyc/block (~5us floor).
//
// R5's staging regression root-caused: it scattered float4-of-f to 4
// b32 writes at stride 292 -> bank (16m+k)%32 = 8-way conflict on b32
// writes. R10 stages by GATHER instead: thread t owns (f=t&63, k-quad),
// reads 4 dwords of w[.][f] column-wise (lane-consecutive f -> 256B
// coalesced global loads), writes ONE b128 at wT[f][4kq] (inherent
// 8-cyc/1024B b128 pattern, no excess conflict).
//
//  * wT row pitch = 292 dwords (1168 B, 16B-aligned); 74752 B LDS,
//    2 blocks/CU -> 16 waves/CU.
//  * TPB=512, PIX=2, 450 blocks (R4's proven config).
//  * x via readfirstlane -> s_load (SGPR broadcast), max3/min3.

#define TPB 512  // 8 waves
#define PIX 2
#define WP  292  // wT row pitch in dwords: 288 + 4 pad, 16B-aligned

__device__ __forceinline__ float fmax3(float a, float b, float c) {
    return fmaxf(fmaxf(a, b), c);
}
__device__ __forceinline__ float fmin3(float a, float b, float c) {
    return fminf(fminf(a, b), c);
}

__global__ __launch_bounds__(TPB) void trop_kernel(
    const float* __restrict__ x,     // (8,32,32,32)
    const float* __restrict__ w,     // (288,64)
    const float* __restrict__ bias,  // (64,)
    float* __restrict__ out)         // (7200,64)
{
    extern __shared__ float wlds[];  // wT[f][k]: 64 rows x 292 pitch = 74752 B

    const int tid  = threadIdx.x;
    const int lane = tid & 63;
    const int wv   = tid >> 6;

    const int pix0 = blockIdx.x * (8 * PIX) + wv * PIX;  // 0..7198

    // Stage w TRANSPOSED, conflict-free.
    // Thread t owns f = t&63 and k-quads kq = (t>>6) + 8i, i = 0..8.
    // Reads: w[4kq+j][f] -- lanes have consecutive f -> 256B coalesced.
    // Write: one b128 per quad at wT[f][4kq].
    {
        const int f  = lane;   // t & 63
        const int q0 = wv;     // t >> 6
#pragma unroll
        for (int i = 0; i < 9; ++i) {
            const int kq = q0 + 8 * i;       // 0..71, unique per (f, kq)
            const int k = 4 * kq;
            float4 v;
            v.x = w[(k + 0) * 64 + f];
            v.y = w[(k + 1) * 64 + f];
            v.z = w[(k + 2) * 64 + f];
            v.w = w[(k + 3) * 64 + f];
            *(float4*)(wlds + f * WP + k) = v;
        }
    }

    // Wave-uniform x base offsets (SGPR) -> s_load x path (R4's winner).
    int xoffp[PIX];
#pragma unroll
    for (int p = 0; p < PIX; ++p) {
        const int pid = pix0 + p;
        const int wo = pid % 30;
        const int t  = pid / 30;
        const int ho = t % 30;
        const int b  = t / 30;
        xoffp[p] = __builtin_amdgcn_readfirstlane((((b * 32 + ho) * 32) + wo) * 32);
    }

    float amax[PIX], amin[PIX];
#pragma unroll
    for (int p = 0; p < PIX; ++p) { amax[p] = -INFINITY; amin[p] = INFINITY; }

    __syncthreads();  // the only barrier

    const float* wrow = wlds + lane * WP;  // this lane's filter row

#pragma unroll
    for (int tap = 0; tap < 9; ++tap) {
        const int dy = tap / 3;
        const int dx = tap % 3;
        const int xoff = (dy * 32 + dx) * 32;
#pragma unroll
        for (int c = 0; c < 32; c += 4) {
            // ONE ds_read_b128: this lane's w[tap*32+c .. +3] (contiguous).
            const float4 wv4 = *(const float4*)(wrow + tap * 32 + c);
#pragma unroll
            for (int p = 0; p < PIX; ++p) {
                const float* xb = x + xoffp[p] + xoff;  // scalar (SGPR) address
                const float s0 = xb[c + 0] + wv4.x;
                const float s1 = xb[c + 1] + wv4.y;
                const float s2 = xb[c + 2] + wv4.z;
                const float s3 = xb[c + 3] + wv4.w;
                amax[p] = fmax3(amax[p], fmax3(s0, s1, s2), s3);
                amin[p] = fmin3(amin[p], fmin3(s0, s1, s2), s3);
            }
        }
    }

    const float bv = bias[lane];
#pragma unroll
    for (int p = 0; p < PIX; ++p)
        out[(pix0 + p) * 64 + lane] = amax[p] - amin[p] + bv;
}

extern "C" void kernel_launch(void* const* d_in, const int* in_sizes, int n_in,
                              void* d_out, int out_size, void* d_ws, size_t ws_size,
                              hipStream_t stream) {
    const float* x    = (const float*)d_in[0];
    const float* w    = (const float*)d_in[1];
    const float* bias = (const float*)d_in[2];
    float* out = (float*)d_out;

    // 74752 B dynamic LDS -> 2 blocks/CU on 160 KiB.
    static int attr_done = 0;
    if (!attr_done) {
        (void)hipFuncSetAttribute((const void*)trop_kernel,
                                  hipFuncAttributeMaxDynamicSharedMemorySize,
                                  74752);
        attr_done = 1;
    }

    // 7200 pixels / (8 waves * 2 pixels) = 450 blocks
    trop_kernel<<<dim3(450), dim3(TPB), 74752, stream>>>(x, w, bias, out);
}